// Round 15
// baseline (425.755 us; speedup 1.0000x reference)
//
#include <hip/hip_runtime.h>
#include <math.h>

typedef __attribute__((ext_vector_type(8))) short bf16x8;
typedef __attribute__((ext_vector_type(4))) float f32x4;
typedef __attribute__((ext_vector_type(16))) float f32x16;

#define NB 4
#define NL 2048
#define ND 2048
#define NH 16
#define NDH 128
#define NDC 512
#define NROWS (NB*NL)

__device__ __forceinline__ unsigned short f2bf(float f) {
  unsigned int u = __float_as_uint(f);
  u += 0x7fffu + ((u >> 16) & 1u);
  return (unsigned short)(u >> 16);
}
__device__ __forceinline__ float bf2f(unsigned short h) {
  return __uint_as_float(((unsigned int)h) << 16);
}
__device__ __forceinline__ unsigned int cvtpk(float lo, float hi) {
  unsigned int r;
  asm("v_cvt_pk_bf16_f32 %0, %1, %2" : "=v"(r) : "v"(lo), "v"(hi));
  return r;
}
// v_permlane32_swap_b32: a.lanes[32:63] <-> b.lanes[0:31]
__device__ __forceinline__ void permswap(unsigned int &a, unsigned int &b) {
  asm("v_permlane32_swap_b32 %0, %1" : "+v"(a), "+v"(b));
}
__device__ __forceinline__ float exp2_fast(float x) {
  float r; asm("v_exp_f32 %0, %1" : "=v"(r) : "v"(x)); return r;
}

__device__ __forceinline__ void gld16(const void* g, void* l) {
  __builtin_amdgcn_global_load_lds((const __attribute__((address_space(1))) void*)g,
                                   (__attribute__((address_space(3))) void*)l, 16, 0, 0);
}

// ---------------- fused fp32 -> bf16 convert: blockIdx.y = segment (no search) ----------------
struct Cvt6 {
  const float4* s[6];
  ushort4* d[6];
  int n4[6];
};
__global__ void cvt6_kernel(Cvt6 cv) {
  const int seg = blockIdx.y;
  const float4* __restrict__ in = cv.s[seg];
  ushort4* __restrict__ out = cv.d[seg];
  const int n4 = cv.n4[seg];
  int stride = gridDim.x * blockDim.x;
  for (int i = blockIdx.x * blockDim.x + threadIdx.x; i < n4; i += stride) {
    float4 v = in[i];
    ushort4 o;
    o.x = f2bf(v.x); o.y = f2bf(v.y); o.z = f2bf(v.z); o.w = f2bf(v.w);
    out[i] = o;
  }
}

// ---------------- 256^2 8-phase NT GEMM (T1+T2+T3+T4+T5), 2-group grouped variant ----------
// Groups share A and K. Group = (bn >= NSPLIT): selects B, C, output width, rope flag.
// bf16 out: LDS-staged coalesced epilogue, optional fused RoPE (group 1 only).
// f32 out: two-pass LDS-staged coalesced epilogue.
template<int OUT_F32>
__global__ __launch_bounds__(512) void gemm_nt256m(const unsigned short* __restrict__ A,
                                                   const unsigned short* __restrict__ B1,
                                                   const unsigned short* __restrict__ B2,
                                                   void* __restrict__ C1,
                                                   void* __restrict__ C2,
                                                   int M, int N1, int N2, int K, int NSPLIT,
                                                   int rope1,
                                                   const float* __restrict__ cosb,
                                                   const float* __restrict__ sinb,
                                                   float rscale) {
  __shared__ unsigned short lds[2][2][16384];   // [buf][0=A,1=B][256 rows x 64 cols]
  const int tid = threadIdx.x;
  const int wid = tid >> 6, lane = tid & 63;
  const int wm = wid >> 2, wn = wid & 3;
  const int r15 = lane & 15, khi = lane >> 4;

  const int gx = gridDim.x;
  int bid = blockIdx.y * gx + blockIdx.x;
  int cpx = (gx * gridDim.y) >> 3;
  int swz = (bid & 7) * cpx + (bid >> 3);
  const long bm = swz / gx, bn = swz % gx;

  // group routing (all wave-uniform)
  const int grp = (bn >= NSPLIT);
  const unsigned short* Bbase = grp ? B2 : B1;
  void* Cout = grp ? C2 : C1;
  const long Nout = grp ? N2 : N1;
  const long gbn = grp ? (bn - NSPLIT) : bn;
  const int do_rope = (!grp) && rope1;

  const int c0 = tid, c1 = 512 + tid;
  const int r0 = c0 >> 3, r1 = c1 >> 3;
  const int cs0 = ((c0 & 7) ^ (r0 & 7)) * 8;
  const int cs1 = ((c1 & 7) ^ (r1 & 7)) * 8;
  const unsigned short* srcA = A + (bm * 256) * (long)K;
  const unsigned short* srcB = Bbase + (gbn * 256) * (long)K;

#define STAGE256(mat, h, kb, bufi) do {                                              \
    const unsigned short* s_ = (mat) ? srcB : srcA;                                  \
    gld16(s_ + ((h) * 128 + r0) * (long)K + (kb) + cs0,                              \
          &lds[bufi][mat][(h) * 8192 + wid * 512]);                                  \
    gld16(s_ + ((h) * 128 + r1) * (long)K + (kb) + cs1,                              \
          &lds[bufi][mat][(h) * 8192 + 4096 + wid * 512]);                           \
  } while (0)

  f32x4 acc[8][4];
#pragma unroll
  for (int m = 0; m < 8; ++m)
#pragma unroll
    for (int n = 0; n < 4; ++n) acc[m][n] = (f32x4){0.f, 0.f, 0.f, 0.f};

  const int NT = K >> 6;
  STAGE256(0, 0, 0, 0); STAGE256(0, 1, 0, 0);
  STAGE256(1, 0, 0, 0); STAGE256(1, 1, 0, 0);

  for (int t = 0; t < NT; ++t) {
    const int buf = t & 1, nbuf = buf ^ 1;
    const int kb1 = (t + 1) << 6;
    const bool pf = (t + 1 < NT);
    __builtin_amdgcn_s_barrier();
    if (pf) {
      STAGE256(0, 0, kb1, nbuf);
      asm volatile("s_waitcnt vmcnt(2)" ::: "memory");
    } else {
      asm volatile("s_waitcnt vmcnt(0)" ::: "memory");
    }
    __builtin_amdgcn_s_barrier();

    bf16x8 bfr[4][2];
#pragma unroll
    for (int n = 0; n < 4; ++n)
#pragma unroll
      for (int kk = 0; kk < 2; ++kk) {
        int rb = wn * 64 + n * 16 + r15;
        bfr[n][kk] = *(const bf16x8*)&lds[buf][1][rb * 64 + (((kk * 4 + khi) ^ (rb & 7)) * 8)];
      }
#pragma unroll
    for (int mb = 0; mb < 4; ++mb) {
      if (mb != 0) {
        __builtin_amdgcn_s_barrier();
        if (pf) {
          if (mb == 1) STAGE256(0, 1, kb1, nbuf);
          else if (mb == 2) STAGE256(1, 0, kb1, nbuf);
          else STAGE256(1, 1, kb1, nbuf);
        }
      }
      bf16x8 af[2][2];
#pragma unroll
      for (int m2 = 0; m2 < 2; ++m2)
#pragma unroll
        for (int kk = 0; kk < 2; ++kk) {
          int ra = wm * 128 + mb * 32 + m2 * 16 + r15;
          af[m2][kk] = *(const bf16x8*)&lds[buf][0][ra * 64 + (((kk * 4 + khi) ^ (ra & 7)) * 8)];
        }
      asm volatile("s_waitcnt lgkmcnt(0)" ::: "memory");
      __builtin_amdgcn_sched_barrier(0);
      __builtin_amdgcn_s_setprio(1);
#pragma unroll
      for (int m2 = 0; m2 < 2; ++m2)
#pragma unroll
        for (int n = 0; n < 4; ++n)
#pragma unroll
          for (int kk = 0; kk < 2; ++kk)
            acc[mb * 2 + m2][n] = __builtin_amdgcn_mfma_f32_16x16x32_bf16(
                af[m2][kk], bfr[n][kk], acc[mb * 2 + m2][n], 0, 0, 0);
      __builtin_amdgcn_s_setprio(0);
    }
  }
#undef STAGE256

  if (!OUT_F32) {
    // ---- LDS-staged bf16 epilogue (coalesced), optional rotary ----
    __syncthreads();
    unsigned short* scr = (unsigned short*)lds;   // col ^ ((row>>2)&3)<<4 swizzle
#pragma unroll
    for (int mi = 0; mi < 8; ++mi)
#pragma unroll
      for (int n = 0; n < 4; ++n) {
        int coll = wn * 64 + n * 16 + r15;
#pragma unroll
        for (int r = 0; r < 4; ++r) {
          int rowl = wm * 128 + mi * 16 + khi * 4 + r;
          scr[rowl * 256 + (coll ^ (((rowl >> 2) & 3) << 4))] = f2bf(acc[mi][n][r]);
        }
      }
    __syncthreads();
    const int d8 = (tid & 7) * 8;
#pragma unroll
    for (int j = 0; j < 8; ++j) {
      int rh = j * 64 + (tid >> 3);
      int rowl = rh >> 1, head = rh & 1;
      long grow = bm * 256 + rowl;
      int sw = ((rowl >> 2) & 3) << 4;
      int cl_ = head * 128 + d8;
      bf16x8 qlo = *(const bf16x8*)(scr + rowl * 256 + (cl_ ^ sw));
      bf16x8 qhi = *(const bf16x8*)(scr + rowl * 256 + ((cl_ + 64) ^ sw));
      bf16x8 olo, ohi;
      if (do_rope) {
        const float* cr = cosb + grow * NDH;
        const float* sr = sinb + grow * NDH;
        float4 cA = *(const float4*)(cr + d8), cB = *(const float4*)(cr + d8 + 4);
        float4 cC = *(const float4*)(cr + d8 + 64), cD = *(const float4*)(cr + d8 + 68);
        float4 sA = *(const float4*)(sr + d8), sB = *(const float4*)(sr + d8 + 4);
        float4 sC = *(const float4*)(sr + d8 + 64), sD = *(const float4*)(sr + d8 + 68);
        float clo[8] = {cA.x, cA.y, cA.z, cA.w, cB.x, cB.y, cB.z, cB.w};
        float chi[8] = {cC.x, cC.y, cC.z, cC.w, cD.x, cD.y, cD.z, cD.w};
        float slo[8] = {sA.x, sA.y, sA.z, sA.w, sB.x, sB.y, sB.z, sB.w};
        float shi[8] = {sC.x, sC.y, sC.z, sC.w, sD.x, sD.y, sD.z, sD.w};
#pragma unroll
        for (int i = 0; i < 8; ++i) {
          float q1 = bf2f((unsigned short)qlo[i]);
          float q2 = bf2f((unsigned short)qhi[i]);
          olo[i] = (short)f2bf((q1 * clo[i] - q2 * slo[i]) * rscale);
          ohi[i] = (short)f2bf((q2 * chi[i] + q1 * shi[i]) * rscale);
        }
      } else {
        olo = qlo;
        ohi = qhi;
      }
      unsigned short* op = (unsigned short*)Cout + grow * Nout + gbn * 256 + cl_;
      *(bf16x8*)op = olo;
      *(bf16x8*)(op + 64) = ohi;
    }
  } else {
    // ---- two-pass LDS-staged f32 epilogue (coalesced 1KB/wave stores) ----
    float* scr32 = (float*)lds;   // 128 rows x 256 cols f32 = 128KB
#pragma unroll
    for (int pass = 0; pass < 2; ++pass) {
      __syncthreads();
      if (wm == pass) {
#pragma unroll
        for (int mi = 0; mi < 8; ++mi)
#pragma unroll
          for (int n = 0; n < 4; ++n) {
            int coll = wn * 64 + n * 16 + r15;
#pragma unroll
            for (int r = 0; r < 4; ++r) {
              int rowl = mi * 16 + khi * 4 + r;    // 0..127 within half
              scr32[rowl * 256 + (coll ^ (((rowl >> 2) & 3) << 4))] = acc[mi][n][r];
            }
          }
      }
      __syncthreads();
#pragma unroll
      for (int j = 0; j < 16; ++j) {
        int rowl = j * 8 + wid;
        int sw = ((rowl >> 2) & 3) << 4;
        float4 v = *(const float4*)(scr32 + rowl * 256 + ((lane * 4) ^ sw));
        *(float4*)((float*)Cout + (bm * 256 + pass * 128 + rowl) * Nout + gbn * 256 + lane * 4) = v;
      }
    }
  }
}

// ---------------- Flash attention v8 (proven config, unchanged) ----------------
__global__ __launch_bounds__(512) void flash_attn(const unsigned short* __restrict__ Qb,
                                                  const unsigned short* __restrict__ Kb,
                                                  const unsigned short* __restrict__ Vb,
                                                  unsigned short* __restrict__ Ob) {
  __shared__ unsigned short KsArr[2 * 8192];   // [buf][key*128 + (c ^ ((key&15)<<3))]
  __shared__ unsigned int VtArr[2 * 4608];     // [buf][d*36 + 4*((kp>>2)^((d>>3)&7)) + (kp&3)]

  const int tid = threadIdx.x, wid = tid >> 6, lane = tid & 63;
  const int l31 = lane & 31, hi5 = lane >> 5;

  const int L = blockIdx.y * 8 + blockIdx.x;
  const int bh = ((L >> 6) << 3) | (L & 7);
  const int qt = (L >> 3) & 7;
  const int b = bh >> 4, h = bh & 15;
  const long rowbase = (long)b * NL;
  const int colbase = h * NDH;
  const long q0 = (long)qt * 256 + wid * 32;

  bf16x8 qf[8];
  {
    const unsigned short* qp = Qb + (rowbase + q0 + l31) * (long)ND + colbase + hi5 * 8;
#pragma unroll
    for (int kc = 0; kc < 8; ++kc) qf[kc] = *(const bf16x8*)(qp + kc * 16);
  }

  f32x16 oacc[4];
#pragma unroll
  for (int db = 0; db < 4; ++db)
#pragma unroll
    for (int i = 0; i < 16; ++i) oacc[db][i] = 0.f;
  float mrun = -1e30f, lrun = 0.f;

  const int kp = tid >> 4;                 // 0..31
  const int c8 = (tid & 15) * 8;
  bf16x8 kreg[2], vreg[2];

#define LOAD_KV(kt_) do {                                                          \
    _Pragma("unroll") for (int j = 0; j < 2; ++j) {                                \
      const long grow = (rowbase + (kt_) * 64 + 2 * kp + j) * (long)ND + colbase + c8; \
      kreg[j] = *(const bf16x8*)(Kb + grow);                                       \
      vreg[j] = *(const bf16x8*)(Vb + grow);                                       \
    } } while (0)

#define WRITE_KV(bi) do {                                                          \
    _Pragma("unroll") for (int j = 0; j < 2; ++j) {                                \
      int row_ = 2 * kp + j;                                                       \
      *(bf16x8*)(KsArr + (bi) * 8192 + row_ * 128 + (c8 ^ ((row_ & 15) << 3))) = kreg[j]; \
    }                                                                              \
    _Pragma("unroll") for (int i = 0; i < 8; ++i) {                                \
      int d_ = c8 + i;                                                             \
      VtArr[(bi) * 4608 + d_ * 36 + 4 * ((kp >> 2) ^ ((d_ >> 3) & 7)) + (kp & 3)] = \
          (unsigned int)(unsigned short)vreg[0][i] |                               \
          ((unsigned int)(unsigned short)vreg[1][i] << 16);                        \
    } } while (0)

  LOAD_KV(0);
  WRITE_KV(0);
  __syncthreads();
  LOAD_KV(1);

  const int NT = NL / 64;
  for (int kt = 0; kt < NT; ++kt) {
    const int bf = kt & 1;
    const unsigned short* Ksb = KsArr + bf * 8192;
    const unsigned int* Vtb = VtArr + bf * 4608;

    f32x16 sacc[2];
    __builtin_amdgcn_s_setprio(1);
#pragma unroll
    for (int nb = 0; nb < 2; ++nb) {
#pragma unroll
      for (int i = 0; i < 16; ++i) sacc[nb][i] = 0.f;
#pragma unroll
      for (int kc = 0; kc < 8; ++kc) {
        int row = nb * 32 + l31;
        bf16x8 kf = *(const bf16x8*)(Ksb + row * 128 + ((kc * 16 + hi5 * 8) ^ ((row & 15) << 3)));
        sacc[nb] = __builtin_amdgcn_mfma_f32_32x32x16_bf16(kf, qf[kc], sacc[nb], 0, 0, 0);
      }
    }
    __builtin_amdgcn_s_setprio(0);

    if (kt + 1 < NT) WRITE_KV(bf ^ 1);
    if (kt + 2 < NT) LOAD_KV(kt + 2);

    float mxa[8];
#pragma unroll
    for (int i = 0; i < 8; ++i)
      mxa[i] = fmaxf(fmaxf(sacc[0][i], sacc[0][i + 8]), fmaxf(sacc[1][i], sacc[1][i + 8]));
    float mx = fmaxf(fmaxf(fmaxf(mxa[0], mxa[1]), fmaxf(mxa[2], mxa[3])),
                     fmaxf(fmaxf(mxa[4], mxa[5]), fmaxf(mxa[6], mxa[7])));
    mx = fmaxf(mx, __shfl_xor(mx, 32));
    if (!__all(mx - mrun <= 8.f)) {            // defer-max (T13)
      float mnew = fmaxf(mrun, mx);
      float corr = exp2_fast(mrun - mnew);
      mrun = mnew;
      lrun *= corr;
#pragma unroll
      for (int db = 0; db < 4; ++db)
#pragma unroll
        for (int i = 0; i < 16; ++i) oacc[db][i] *= corr;
    }
    float s4[4] = {0.f, 0.f, 0.f, 0.f};
#pragma unroll
    for (int nb = 0; nb < 2; ++nb)
#pragma unroll
      for (int r = 0; r < 16; ++r) {
        float e = exp2_fast(sacc[nb][r] - mrun);
        sacc[nb][r] = e;
        s4[r & 3] += e;
      }
    float s = (s4[0] + s4[1]) + (s4[2] + s4[3]);
    s += __shfl_xor(s, 32);
    lrun += s;

    union { unsigned int u[4]; bf16x8 v; } pa[2][2];
#pragma unroll
    for (int nb = 0; nb < 2; ++nb) {
      unsigned int x1 = cvtpk(sacc[nb][0], sacc[nb][1]);
      unsigned int x2 = cvtpk(sacc[nb][2], sacc[nb][3]);
      unsigned int y1 = cvtpk(sacc[nb][4], sacc[nb][5]);
      unsigned int y2 = cvtpk(sacc[nb][6], sacc[nb][7]);
      unsigned int z1 = cvtpk(sacc[nb][8], sacc[nb][9]);
      unsigned int z2 = cvtpk(sacc[nb][10], sacc[nb][11]);
      unsigned int w1 = cvtpk(sacc[nb][12], sacc[nb][13]);
      unsigned int w2 = cvtpk(sacc[nb][14], sacc[nb][15]);
      permswap(x1, y1);
      permswap(x2, y2);
      permswap(z1, w1);
      permswap(z2, w2);
      pa[nb][0].u[0] = x1; pa[nb][0].u[1] = x2; pa[nb][0].u[2] = y1; pa[nb][0].u[3] = y2;
      pa[nb][1].u[0] = z1; pa[nb][1].u[1] = z2; pa[nb][1].u[2] = w1; pa[nb][1].u[3] = w2;
    }

    __builtin_amdgcn_s_setprio(1);
#pragma unroll
    for (int db = 0; db < 4; ++db) {
      int d = db * 32 + l31;
      int dsw = (d >> 3) & 7;
#pragma unroll
      for (int nb = 0; nb < 2; ++nb)
#pragma unroll
        for (int ks = 0; ks < 2; ++ks) {
          int g = nb * 4 + ks * 2 + hi5;
          bf16x8 vf = *(const bf16x8*)(Vtb + d * 36 + 4 * (g ^ dsw));
          oacc[db] = __builtin_amdgcn_mfma_f32_32x32x16_bf16(vf, pa[nb][ks].v, oacc[db], 0, 0, 0);
        }
    }
    __builtin_amdgcn_s_setprio(0);
    __syncthreads();
  }
#undef LOAD_KV
#undef WRITE_KV

  float rinv = 1.0f / lrun;
  unsigned short* scr = (unsigned short*)VtArr + wid * 2304;   // 32 rows x 72
#pragma unroll
  for (int c = 0; c < 2; ++c) {
    asm volatile("s_waitcnt lgkmcnt(0)" ::: "memory");
    __builtin_amdgcn_sched_barrier(0);
#pragma unroll
    for (int dbh = 0; dbh < 2; ++dbh) {
      int db = 2 * c + dbh;
#pragma unroll
      for (int t = 0; t < 8; ++t) {
        int d_lo = dbh * 32 + ((2 * t) & 3) + 8 * (t >> 1) + 4 * hi5;
        unsigned int pv = cvtpk(oacc[db][2 * t] * rinv, oacc[db][2 * t + 1] * rinv);
        *(unsigned int*)(scr + l31 * 72 + d_lo) = pv;
      }
    }
    asm volatile("s_waitcnt lgkmcnt(0)" ::: "memory");
    __builtin_amdgcn_sched_barrier(0);
#pragma unroll
    for (int j = 0; j < 4; ++j) {
      int row = j * 8 + (lane >> 3);
      bf16x8 ov = *(const bf16x8*)(scr + row * 72 + (lane & 7) * 8);
      *(bf16x8*)(Ob + (rowbase + q0 + row) * (long)ND + colbase + c * 64 + (lane & 7) * 8) = ov;
    }
  }
}

// ---------------- launch ----------------
extern "C" void kernel_launch(void* const* d_in, const int* in_sizes, int n_in,
                              void* d_out, int out_size, void* d_ws, size_t ws_size,
                              hipStream_t stream) {
  const float* x = (const float*)d_in[0];
  const float* rope_cos = (const float*)d_in[1];
  const float* rope_sin = (const float*)d_in[2];
  const float* W_q = (const float*)d_in[3];
  const float* W_dkv = (const float*)d_in[4];
  const float* W_uk = (const float*)d_in[5];
  const float* W_uv = (const float*)d_in[6];
  const float* W_o = (const float*)d_in[7];
  float* out = (float*)d_out;

  char* p = (char*)d_ws;
  unsigned short* xb = (unsigned short*)p;    p += (size_t)NROWS * ND * 2;
  unsigned short* Wqb = (unsigned short*)p;   p += (size_t)ND * ND * 2;
  unsigned short* Wdkvb = (unsigned short*)p; p += (size_t)NDC * ND * 2;
  unsigned short* Wukb = (unsigned short*)p;  p += (size_t)ND * NDC * 2;
  unsigned short* Wuvb = (unsigned short*)p;  p += (size_t)ND * NDC * 2;
  unsigned short* Wob = (unsigned short*)p;   p += (size_t)ND * ND * 2;
  unsigned short* Qb = (unsigned short*)p;    p += (size_t)NROWS * ND * 2;
  unsigned short* ckv = (unsigned short*)p;   p += (size_t)NROWS * NDC * 2;
  unsigned short* Kbf = (unsigned short*)p;   p += (size_t)NROWS * ND * 2;
  unsigned short* Vbf = (unsigned short*)p;   p += (size_t)NROWS * ND * 2;
  unsigned short* AO = (unsigned short*)p;    p += (size_t)NROWS * ND * 2;

  // fused fp32 -> bf16: one dispatch, blockIdx.y = segment
  {
    Cvt6 cv;
    const float* ss[6] = {x, W_q, W_dkv, W_uk, W_uv, W_o};
    unsigned short* dd[6] = {xb, Wqb, Wdkvb, Wukb, Wuvb, Wob};
    long nn[6] = {(long)NROWS * ND, (long)ND * ND, (long)NDC * ND,
                  (long)ND * NDC, (long)ND * NDC, (long)ND * ND};
    for (int i = 0; i < 6; ++i) {
      cv.s[i] = (const float4*)ss[i];
      cv.d[i] = (ushort4*)dd[i];
      cv.n4[i] = (int)(nn[i] / 4);
    }
    cvt6_kernel<<<dim3(512, 6), 256, 0, stream>>>(cv);
  }

  // RoPE scales: Q gets 1/sqrt(DH)*log2(e) (flash softmax uses exp2); K gets 1.0
  const float scale_q = 0.08838834764831845f * 1.4426950408889634f;

  // merged Q-proj + dkv-proj (shared A = xb, K = 2048): grid (10, 32) = 320 blocks
  gemm_nt256m<0><<<dim3(10, 32), 512, 0, stream>>>(
      xb, Wqb, Wdkvb, Qb, ckv, NROWS, ND, NDC, ND, 8, 1, rope_cos, rope_sin, scale_q);

  // merged uk + uv (shared A = ckv, K = 512): grid (16, 32) = 512 blocks
  gemm_nt256m<0><<<dim3(16, 32), 512, 0, stream>>>(
      ckv, Wukb, Wuvb, Kbf, Vbf, NROWS, ND, ND, NDC, 8, 1, rope_cos, rope_sin, 1.0f);

  // attention: 512 blocks of 512 threads (QBLK=256, 32 q/wave) — proven v8 config
  flash_attn<<<dim3(8, 64), 512, 0, stream>>>(Qb, Kbf, Vbf, AO);

  // output projection (fp32 out, coalesced LDS epilogue)
  gemm_nt256m<1><<<dim3(8, 32), 512, 0, stream>>>(
      AO, Wob, nullptr, out, nullptr, NROWS, ND, ND, ND, 8, 0, nullptr, nullptr, 0.f);
}

// Round 16
// 421.196 us; speedup vs baseline: 1.0108x; 1.0108x over previous
//
#include <hip/hip_runtime.h>
#include <math.h>

typedef __attribute__((ext_vector_type(8))) short bf16x8;
typedef __attribute__((ext_vector_type(4))) float f32x4;
typedef __attribute__((ext_vector_type(16))) float f32x16;

#define NB 4
#define NL 2048
#define ND 2048
#define NH 16
#define NDH 128
#define NDC 512
#define NROWS (NB*NL)

__device__ __forceinline__ unsigned short f2bf(float f) {
  unsigned int u = __float_as_uint(f);
  u += 0x7fffu + ((u >> 16) & 1u);
  return (unsigned short)(u >> 16);
}
__device__ __forceinline__ float bf2f(unsigned short h) {
  return __uint_as_float(((unsigned int)h) << 16);
}
__device__ __forceinline__ unsigned int cvtpk(float lo, float hi) {
  unsigned int r;
  asm("v_cvt_pk_bf16_f32 %0, %1, %2" : "=v"(r) : "v"(lo), "v"(hi));
  return r;
}
// v_permlane32_swap_b32: a.lanes[32:63] <-> b.lanes[0:31]
__device__ __forceinline__ void permswap(unsigned int &a, unsigned int &b) {
  asm("v_permlane32_swap_b32 %0, %1" : "+v"(a), "+v"(b));
}
__device__ __forceinline__ float exp2_fast(float x) {
  float r; asm("v_exp_f32 %0, %1" : "=v"(r) : "v"(x)); return r;
}

__device__ __forceinline__ void gld16(const void* g, void* l) {
  __builtin_amdgcn_global_load_lds((const __attribute__((address_space(1))) void*)g,
                                   (__attribute__((address_space(3))) void*)l, 16, 0, 0);
}

// ---------------- fused fp32 -> bf16 convert: blockIdx.y = segment (no search) ----------------
struct Cvt6 {
  const float4* s[6];
  ushort4* d[6];
  int n4[6];
};
__global__ void cvt6_kernel(Cvt6 cv) {
  const int seg = blockIdx.y;
  const float4* __restrict__ in = cv.s[seg];
  ushort4* __restrict__ out = cv.d[seg];
  const int n4 = cv.n4[seg];
  int stride = gridDim.x * blockDim.x;
  for (int i = blockIdx.x * blockDim.x + threadIdx.x; i < n4; i += stride) {
    float4 v = in[i];
    ushort4 o;
    o.x = f2bf(v.x); o.y = f2bf(v.y); o.z = f2bf(v.z); o.w = f2bf(v.w);
    out[i] = o;
  }
}

// ---------------- 128^2 NT GEMM (dkv: N=512, 256 full-chip blocks) ----------------
template<int OUT_F32>
__global__ __launch_bounds__(256) void gemm_nt(const unsigned short* __restrict__ A,
                                               const unsigned short* __restrict__ Bm,
                                               void* __restrict__ Cv,
                                               int M, int N, int K) {
  __shared__ unsigned short As[128 * 32];
  __shared__ unsigned short Bs[128 * 32];
  const int tid = threadIdx.x;
  const int wid = tid >> 6;
  const int lane = tid & 63;
  const int wr = wid >> 1, wc = wid & 1;
  const long bm = blockIdx.y, bn = blockIdx.x;
  const int r15 = lane & 15;
  const int koff = (lane >> 4) * 8;
  const int srow = lane >> 2;
  const int scol = (lane & 3) * 8;

  f32x4 acc[4][4];
#pragma unroll
  for (int m = 0; m < 4; ++m)
#pragma unroll
    for (int n = 0; n < 4; ++n) acc[m][n] = (f32x4){0.f, 0.f, 0.f, 0.f};

  const unsigned short* Ablk = A + (bm * 128 + wid * 16 + srow) * (long)K + scol;
  const unsigned short* Bblk = Bm + (bn * 128 + wid * 16 + srow) * (long)K + scol;
  unsigned short* AsW = As + wid * 16 * 32;
  unsigned short* BsW = Bs + wid * 16 * 32;

  for (int kk = 0; kk < K; kk += 32) {
    __syncthreads();
#pragma unroll
    for (int j = 0; j < 2; ++j) {
      gld16(Ablk + (long)j * 64 * K + kk, AsW + j * 64 * 32);
      gld16(Bblk + (long)j * 64 * K + kk, BsW + j * 64 * 32);
    }
    __syncthreads();
    bf16x8 af[4], bfr[4];
#pragma unroll
    for (int m = 0; m < 4; ++m)
      af[m] = *(const bf16x8*)(As + (wr * 64 + m * 16 + r15) * 32 + koff);
#pragma unroll
    for (int n = 0; n < 4; ++n)
      bfr[n] = *(const bf16x8*)(Bs + (wc * 64 + n * 16 + r15) * 32 + koff);
#pragma unroll
    for (int m = 0; m < 4; ++m)
#pragma unroll
      for (int n = 0; n < 4; ++n)
        acc[m][n] = __builtin_amdgcn_mfma_f32_16x16x32_bf16(af[m], bfr[n], acc[m][n], 0, 0, 0);
  }

  const int rr = (lane >> 4) * 4;
#pragma unroll
  for (int m = 0; m < 4; ++m) {
#pragma unroll
    for (int n = 0; n < 4; ++n) {
      long row0 = bm * 128 + wr * 64 + m * 16 + rr;
      long col = bn * 128 + wc * 64 + n * 16 + r15;
#pragma unroll
      for (int r = 0; r < 4; ++r) {
        float v = acc[m][n][r];
        if (OUT_F32) ((float*)Cv)[(row0 + r) * (long)N + col] = v;
        else ((unsigned short*)Cv)[(row0 + r) * (long)N + col] = f2bf(v);
      }
    }
  }
}

// ---------------- 256^2 8-phase NT GEMM (T1+T2+T3+T4+T5), 2-group grouped variant ----------
// Groups share A and K. Group = (bn >= NSPLIT): selects B, C, output width, rope flag.
// Single-group use: NSPLIT >= gridDim.x.
template<int OUT_F32>
__global__ __launch_bounds__(512) void gemm_nt256m(const unsigned short* __restrict__ A,
                                                   const unsigned short* __restrict__ B1,
                                                   const unsigned short* __restrict__ B2,
                                                   void* __restrict__ C1,
                                                   void* __restrict__ C2,
                                                   int M, int N1, int N2, int K, int NSPLIT,
                                                   int rope1,
                                                   const float* __restrict__ cosb,
                                                   const float* __restrict__ sinb,
                                                   float rscale) {
  __shared__ unsigned short lds[2][2][16384];   // [buf][0=A,1=B][256 rows x 64 cols]
  const int tid = threadIdx.x;
  const int wid = tid >> 6, lane = tid & 63;
  const int wm = wid >> 2, wn = wid & 3;
  const int r15 = lane & 15, khi = lane >> 4;

  const int gx = gridDim.x;
  int bid = blockIdx.y * gx + blockIdx.x;
  int cpx = (gx * gridDim.y) >> 3;
  int swz = (bid & 7) * cpx + (bid >> 3);
  const long bm = swz / gx, bn = swz % gx;

  // group routing (all wave-uniform)
  const int grp = (bn >= NSPLIT);
  const unsigned short* Bbase = grp ? B2 : B1;
  void* Cout = grp ? C2 : C1;
  const long Nout = grp ? N2 : N1;
  const long gbn = grp ? (bn - NSPLIT) : bn;
  const int do_rope = (!grp) && rope1;

  const int c0 = tid, c1 = 512 + tid;
  const int r0 = c0 >> 3, r1 = c1 >> 3;
  const int cs0 = ((c0 & 7) ^ (r0 & 7)) * 8;
  const int cs1 = ((c1 & 7) ^ (r1 & 7)) * 8;
  const unsigned short* srcA = A + (bm * 256) * (long)K;
  const unsigned short* srcB = Bbase + (gbn * 256) * (long)K;

#define STAGE256(mat, h, kb, bufi) do {                                              \
    const unsigned short* s_ = (mat) ? srcB : srcA;                                  \
    gld16(s_ + ((h) * 128 + r0) * (long)K + (kb) + cs0,                              \
          &lds[bufi][mat][(h) * 8192 + wid * 512]);                                  \
    gld16(s_ + ((h) * 128 + r1) * (long)K + (kb) + cs1,                              \
          &lds[bufi][mat][(h) * 8192 + 4096 + wid * 512]);                           \
  } while (0)

  f32x4 acc[8][4];
#pragma unroll
  for (int m = 0; m < 8; ++m)
#pragma unroll
    for (int n = 0; n < 4; ++n) acc[m][n] = (f32x4){0.f, 0.f, 0.f, 0.f};

  const int NT = K >> 6;
  STAGE256(0, 0, 0, 0); STAGE256(0, 1, 0, 0);
  STAGE256(1, 0, 0, 0); STAGE256(1, 1, 0, 0);

  for (int t = 0; t < NT; ++t) {
    const int buf = t & 1, nbuf = buf ^ 1;
    const int kb1 = (t + 1) << 6;
    const bool pf = (t + 1 < NT);
    __builtin_amdgcn_s_barrier();
    if (pf) {
      STAGE256(0, 0, kb1, nbuf);
      asm volatile("s_waitcnt vmcnt(2)" ::: "memory");
    } else {
      asm volatile("s_waitcnt vmcnt(0)" ::: "memory");
    }
    __builtin_amdgcn_s_barrier();

    bf16x8 bfr[4][2];
#pragma unroll
    for (int n = 0; n < 4; ++n)
#pragma unroll
      for (int kk = 0; kk < 2; ++kk) {
        int rb = wn * 64 + n * 16 + r15;
        bfr[n][kk] = *(const bf16x8*)&lds[buf][1][rb * 64 + (((kk * 4 + khi) ^ (rb & 7)) * 8)];
      }
#pragma unroll
    for (int mb = 0; mb < 4; ++mb) {
      if (mb != 0) {
        __builtin_amdgcn_s_barrier();
        if (pf) {
          if (mb == 1) STAGE256(0, 1, kb1, nbuf);
          else if (mb == 2) STAGE256(1, 0, kb1, nbuf);
          else STAGE256(1, 1, kb1, nbuf);
        }
      }
      bf16x8 af[2][2];
#pragma unroll
      for (int m2 = 0; m2 < 2; ++m2)
#pragma unroll
        for (int kk = 0; kk < 2; ++kk) {
          int ra = wm * 128 + mb * 32 + m2 * 16 + r15;
          af[m2][kk] = *(const bf16x8*)&lds[buf][0][ra * 64 + (((kk * 4 + khi) ^ (ra & 7)) * 8)];
        }
      asm volatile("s_waitcnt lgkmcnt(0)" ::: "memory");
      __builtin_amdgcn_sched_barrier(0);
      __builtin_amdgcn_s_setprio(1);
#pragma unroll
      for (int m2 = 0; m2 < 2; ++m2)
#pragma unroll
        for (int n = 0; n < 4; ++n)
#pragma unroll
          for (int kk = 0; kk < 2; ++kk)
            acc[mb * 2 + m2][n] = __builtin_amdgcn_mfma_f32_16x16x32_bf16(
                af[m2][kk], bfr[n][kk], acc[mb * 2 + m2][n], 0, 0, 0);
      __builtin_amdgcn_s_setprio(0);
    }
  }
#undef STAGE256

  if (!OUT_F32) {
    // ---- LDS-staged bf16 epilogue (coalesced), optional rotary ----
    __syncthreads();
    unsigned short* scr = (unsigned short*)lds;   // col ^ ((row>>2)&3)<<4 swizzle
#pragma unroll
    for (int mi = 0; mi < 8; ++mi)
#pragma unroll
      for (int n = 0; n < 4; ++n) {
        int coll = wn * 64 + n * 16 + r15;
#pragma unroll
        for (int r = 0; r < 4; ++r) {
          int rowl = wm * 128 + mi * 16 + khi * 4 + r;
          scr[rowl * 256 + (coll ^ (((rowl >> 2) & 3) << 4))] = f2bf(acc[mi][n][r]);
        }
      }
    __syncthreads();
    const int d8 = (tid & 7) * 8;
#pragma unroll
    for (int j = 0; j < 8; ++j) {
      int rh = j * 64 + (tid >> 3);
      int rowl = rh >> 1, head = rh & 1;
      long grow = bm * 256 + rowl;
      int sw = ((rowl >> 2) & 3) << 4;
      int cl_ = head * 128 + d8;
      bf16x8 qlo = *(const bf16x8*)(scr + rowl * 256 + (cl_ ^ sw));
      bf16x8 qhi = *(const bf16x8*)(scr + rowl * 256 + ((cl_ + 64) ^ sw));
      bf16x8 olo, ohi;
      if (do_rope) {
        const float* cr = cosb + grow * NDH;
        const float* sr = sinb + grow * NDH;
        float4 cA = *(const float4*)(cr + d8), cB = *(const float4*)(cr + d8 + 4);
        float4 cC = *(const float4*)(cr + d8 + 64), cD = *(const float4*)(cr + d8 + 68);
        float4 sA = *(const float4*)(sr + d8), sB = *(const float4*)(sr + d8 + 4);
        float4 sC = *(const float4*)(sr + d8 + 64), sD = *(const float4*)(sr + d8 + 68);
        float clo[8] = {cA.x, cA.y, cA.z, cA.w, cB.x, cB.y, cB.z, cB.w};
        float chi[8] = {cC.x, cC.y, cC.z, cC.w, cD.x, cD.y, cD.z, cD.w};
        float slo[8] = {sA.x, sA.y, sA.z, sA.w, sB.x, sB.y, sB.z, sB.w};
        float shi[8] = {sC.x, sC.y, sC.z, sC.w, sD.x, sD.y, sD.z, sD.w};
#pragma unroll
        for (int i = 0; i < 8; ++i) {
          float q1 = bf2f((unsigned short)qlo[i]);
          float q2 = bf2f((unsigned short)qhi[i]);
          olo[i] = (short)f2bf((q1 * clo[i] - q2 * slo[i]) * rscale);
          ohi[i] = (short)f2bf((q2 * chi[i] + q1 * shi[i]) * rscale);
        }
      } else {
        olo = qlo;
        ohi = qhi;
      }
      unsigned short* op = (unsigned short*)Cout + grow * Nout + gbn * 256 + cl_;
      *(bf16x8*)op = olo;
      *(bf16x8*)(op + 64) = ohi;
    }
  } else {
    // ---- two-pass LDS-staged f32 epilogue (coalesced 1KB/wave stores) ----
    float* scr32 = (float*)lds;   // 128 rows x 256 cols f32 = 128KB
#pragma unroll
    for (int pass = 0; pass < 2; ++pass) {
      __syncthreads();
      if (wm == pass) {
#pragma unroll
        for (int mi = 0; mi < 8; ++mi)
#pragma unroll
          for (int n = 0; n < 4; ++n) {
            int coll = wn * 64 + n * 16 + r15;
#pragma unroll
            for (int r = 0; r < 4; ++r) {
              int rowl = mi * 16 + khi * 4 + r;    // 0..127 within half
              scr32[rowl * 256 + (coll ^ (((rowl >> 2) & 3) << 4))] = acc[mi][n][r];
            }
          }
      }
      __syncthreads();
#pragma unroll
      for (int j = 0; j < 16; ++j) {
        int rowl = j * 8 + wid;
        int sw = ((rowl >> 2) & 3) << 4;
        float4 v = *(const float4*)(scr32 + rowl * 256 + ((lane * 4) ^ sw));
        *(float4*)((float*)Cout + (bm * 256 + pass * 128 + rowl) * Nout + gbn * 256 + lane * 4) = v;
      }
    }
  }
}

// ---------------- Flash attention v8 (proven config, unchanged) ----------------
__global__ __launch_bounds__(512) void flash_attn(const unsigned short* __restrict__ Qb,
                                                  const unsigned short* __restrict__ Kb,
                                                  const unsigned short* __restrict__ Vb,
                                                  unsigned short* __restrict__ Ob) {
  __shared__ unsigned short KsArr[2 * 8192];   // [buf][key*128 + (c ^ ((key&15)<<3))]
  __shared__ unsigned int VtArr[2 * 4608];     // [buf][d*36 + 4*((kp>>2)^((d>>3)&7)) + (kp&3)]

  const int tid = threadIdx.x, wid = tid >> 6, lane = tid & 63;
  const int l31 = lane & 31, hi5 = lane >> 5;

  const int L = blockIdx.y * 8 + blockIdx.x;
  const int bh = ((L >> 6) << 3) | (L & 7);
  const int qt = (L >> 3) & 7;
  const int b = bh >> 4, h = bh & 15;
  const long rowbase = (long)b * NL;
  const int colbase = h * NDH;
  const long q0 = (long)qt * 256 + wid * 32;

  bf16x8 qf[8];
  {
    const unsigned short* qp = Qb + (rowbase + q0 + l31) * (long)ND + colbase + hi5 * 8;
#pragma unroll
    for (int kc = 0; kc < 8; ++kc) qf[kc] = *(const bf16x8*)(qp + kc * 16);
  }

  f32x16 oacc[4];
#pragma unroll
  for (int db = 0; db < 4; ++db)
#pragma unroll
    for (int i = 0; i < 16; ++i) oacc[db][i] = 0.f;
  float mrun = -1e30f, lrun = 0.f;

  const int kp = tid >> 4;                 // 0..31
  const int c8 = (tid & 15) * 8;
  bf16x8 kreg[2], vreg[2];

#define LOAD_KV(kt_) do {                                                          \
    _Pragma("unroll") for (int j = 0; j < 2; ++j) {                                \
      const long grow = (rowbase + (kt_) * 64 + 2 * kp + j) * (long)ND + colbase + c8; \
      kreg[j] = *(const bf16x8*)(Kb + grow);                                       \
      vreg[j] = *(const bf16x8*)(Vb + grow);                                       \
    } } while (0)

#define WRITE_KV(bi) do {                                                          \
    _Pragma("unroll") for (int j = 0; j < 2; ++j) {                                \
      int row_ = 2 * kp + j;                                                       \
      *(bf16x8*)(KsArr + (bi) * 8192 + row_ * 128 + (c8 ^ ((row_ & 15) << 3))) = kreg[j]; \
    }                                                                              \
    _Pragma("unroll") for (int i = 0; i < 8; ++i) {                                \
      int d_ = c8 + i;                                                             \
      VtArr[(bi) * 4608 + d_ * 36 + 4 * ((kp >> 2) ^ ((d_ >> 3) & 7)) + (kp & 3)] = \
          (unsigned int)(unsigned short)vreg[0][i] |                               \
          ((unsigned int)(unsigned short)vreg[1][i] << 16);                        \
    } } while (0)

  LOAD_KV(0);
  WRITE_KV(0);
  __syncthreads();
  LOAD_KV(1);

  const int NT = NL / 64;
  for (int kt = 0; kt < NT; ++kt) {
    const int bf = kt & 1;
    const unsigned short* Ksb = KsArr + bf * 8192;
    const unsigned int* Vtb = VtArr + bf * 4608;

    f32x16 sacc[2];
    __builtin_amdgcn_s_setprio(1);
#pragma unroll
    for (int nb = 0; nb < 2; ++nb) {
#pragma unroll
      for (int i = 0; i < 16; ++i) sacc[nb][i] = 0.f;
#pragma unroll
      for (int kc = 0; kc < 8; ++kc) {
        int row = nb * 32 + l31;
        bf16x8 kf = *(const bf16x8*)(Ksb + row * 128 + ((kc * 16 + hi5 * 8) ^ ((row & 15) << 3)));
        sacc[nb] = __builtin_amdgcn_mfma_f32_32x32x16_bf16(kf, qf[kc], sacc[nb], 0, 0, 0);
      }
    }
    __builtin_amdgcn_s_setprio(0);

    if (kt + 1 < NT) WRITE_KV(bf ^ 1);
    if (kt + 2 < NT) LOAD_KV(kt + 2);

    float mxa[8];
#pragma unroll
    for (int i = 0; i < 8; ++i)
      mxa[i] = fmaxf(fmaxf(sacc[0][i], sacc[0][i + 8]), fmaxf(sacc[1][i], sacc[1][i + 8]));
    float mx = fmaxf(fmaxf(fmaxf(mxa[0], mxa[1]), fmaxf(mxa[2], mxa[3])),
                     fmaxf(fmaxf(mxa[4], mxa[5]), fmaxf(mxa[6], mxa[7])));
    mx = fmaxf(mx, __shfl_xor(mx, 32));
    if (!__all(mx - mrun <= 8.f)) {            // defer-max (T13)
      float mnew = fmaxf(mrun, mx);
      float corr = exp2_fast(mrun - mnew);
      mrun = mnew;
      lrun *= corr;
#pragma unroll
      for (int db = 0; db < 4; ++db)
#pragma unroll
        for (int i = 0; i < 16; ++i) oacc[db][i] *= corr;
    }
    float s4[4] = {0.f, 0.f, 0.f, 0.f};
#pragma unroll
    for (int nb = 0; nb < 2; ++nb)
#pragma unroll
      for (int r = 0; r < 16; ++r) {
        float e = exp2_fast(sacc[nb][r] - mrun);
        sacc[nb][r] = e;
        s4[r & 3] += e;
      }
    float s = (s4[0] + s4[1]) + (s4[2] + s4[3]);
    s += __shfl_xor(s, 32);
    lrun += s;

    union { unsigned int u[4]; bf16x8 v; } pa[2][2];
#pragma unroll
    for (int nb = 0; nb < 2; ++nb) {
      unsigned int x1 = cvtpk(sacc[nb][0], sacc[nb][1]);
      unsigned int x2 = cvtpk(sacc[nb][2], sacc[nb][3]);
      unsigned int y1 = cvtpk(sacc[nb][4], sacc[nb][5]);
      unsigned int y2 = cvtpk(sacc[nb][6], sacc[nb][7]);
      unsigned int z1 = cvtpk(sacc[nb][8], sacc[nb][9]);
      unsigned int z2 = cvtpk(sacc[nb][10], sacc[nb][11]);
      unsigned int w1 = cvtpk(sacc[nb][12], sacc[nb][13]);
      unsigned int w2 = cvtpk(sacc[nb][14], sacc[nb][15]);
      permswap(x1, y1);
      permswap(x2, y2);
      permswap(z1, w1);
      permswap(z2, w2);
      pa[nb][0].u[0] = x1; pa[nb][0].u[1] = x2; pa[nb][0].u[2] = y1; pa[nb][0].u[3] = y2;
      pa[nb][1].u[0] = z1; pa[nb][1].u[1] = z2; pa[nb][1].u[2] = w1; pa[nb][1].u[3] = w2;
    }

    __builtin_amdgcn_s_setprio(1);
#pragma unroll
    for (int db = 0; db < 4; ++db) {
      int d = db * 32 + l31;
      int dsw = (d >> 3) & 7;
#pragma unroll
      for (int nb = 0; nb < 2; ++nb)
#pragma unroll
        for (int ks = 0; ks < 2; ++ks) {
          int g = nb * 4 + ks * 2 + hi5;
          bf16x8 vf = *(const bf16x8*)(Vtb + d * 36 + 4 * (g ^ dsw));
          oacc[db] = __builtin_amdgcn_mfma_f32_32x32x16_bf16(vf, pa[nb][ks].v, oacc[db], 0, 0, 0);
        }
    }
    __builtin_amdgcn_s_setprio(0);
    __syncthreads();
  }
#undef LOAD_KV
#undef WRITE_KV

  float rinv = 1.0f / lrun;
  unsigned short* scr = (unsigned short*)VtArr + wid * 2304;   // 32 rows x 72
#pragma unroll
  for (int c = 0; c < 2; ++c) {
    asm volatile("s_waitcnt lgkmcnt(0)" ::: "memory");
    __builtin_amdgcn_sched_barrier(0);
#pragma unroll
    for (int dbh = 0; dbh < 2; ++dbh) {
      int db = 2 * c + dbh;
#pragma unroll
      for (int t = 0; t < 8; ++t) {
        int d_lo = dbh * 32 + ((2 * t) & 3) + 8 * (t >> 1) + 4 * hi5;
        unsigned int pv = cvtpk(oacc[db][2 * t] * rinv, oacc[db][2 * t + 1] * rinv);
        *(unsigned int*)(scr + l31 * 72 + d_lo) = pv;
      }
    }
    asm volatile("s_waitcnt lgkmcnt(0)" ::: "memory");
    __builtin_amdgcn_sched_barrier(0);
#pragma unroll
    for (int j = 0; j < 4; ++j) {
      int row = j * 8 + (lane >> 3);
      bf16x8 ov = *(const bf16x8*)(scr + row * 72 + (lane & 7) * 8);
      *(bf16x8*)(Ob + (rowbase + q0 + row) * (long)ND + colbase + c * 64 + (lane & 7) * 8) = ov;
    }
  }
}

// ---------------- launch ----------------
extern "C" void kernel_launch(void* const* d_in, const int* in_sizes, int n_in,
                              void* d_out, int out_size, void* d_ws, size_t ws_size,
                              hipStream_t stream) {
  const float* x = (const float*)d_in[0];
  const float* rope_cos = (const float*)d_in[1];
  const float* rope_sin = (const float*)d_in[2];
  const float* W_q = (const float*)d_in[3];
  const float* W_dkv = (const float*)d_in[4];
  const float* W_uk = (const float*)d_in[5];
  const float* W_uv = (const float*)d_in[6];
  const float* W_o = (const float*)d_in[7];
  float* out = (float*)d_out;

  char* p = (char*)d_ws;
  unsigned short* xb = (unsigned short*)p;    p += (size_t)NROWS * ND * 2;
  unsigned short* Wqb = (unsigned short*)p;   p += (size_t)ND * ND * 2;
  unsigned short* Wdkvb = (unsigned short*)p; p += (size_t)NDC * ND * 2;
  unsigned short* Wukb = (unsigned short*)p;  p += (size_t)ND * NDC * 2;
  unsigned short* Wuvb = (unsigned short*)p;  p += (size_t)ND * NDC * 2;
  unsigned short* Wob = (unsigned short*)p;   p += (size_t)ND * ND * 2;
  unsigned short* Qb = (unsigned short*)p;    p += (size_t)NROWS * ND * 2;
  unsigned short* ckv = (unsigned short*)p;   p += (size_t)NROWS * NDC * 2;
  unsigned short* Kbf = (unsigned short*)p;   p += (size_t)NROWS * ND * 2;
  unsigned short* Vbf = (unsigned short*)p;   p += (size_t)NROWS * ND * 2;
  unsigned short* AO = (unsigned short*)p;    p += (size_t)NROWS * ND * 2;

  // fused fp32 -> bf16: one dispatch, blockIdx.y = segment
  {
    Cvt6 cv;
    const float* ss[6] = {x, W_q, W_dkv, W_uk, W_uv, W_o};
    unsigned short* dd[6] = {xb, Wqb, Wdkvb, Wukb, Wuvb, Wob};
    long nn[6] = {(long)NROWS * ND, (long)ND * ND, (long)NDC * ND,
                  (long)ND * NDC, (long)ND * NDC, (long)ND * ND};
    for (int i = 0; i < 6; ++i) {
      cv.s[i] = (const float4*)ss[i];
      cv.d[i] = (ushort4*)dd[i];
      cv.n4[i] = (int)(nn[i] / 4);
    }
    cvt6_kernel<<<dim3(512, 6), 256, 0, stream>>>(cv);
  }

  // RoPE scales: Q gets 1/sqrt(DH)*log2(e) (flash softmax uses exp2); K gets 1.0
  const float scale_q = 0.08838834764831845f * 1.4426950408889634f;

  // Q-proj with fused rope: 256 full-chip blocks (single group)
  gemm_nt256m<0><<<dim3(8, 32), 512, 0, stream>>>(
      xb, Wqb, nullptr, Qb, nullptr, NROWS, ND, ND, ND, 8, 1, rope_cos, rope_sin, scale_q);

  // dkv on 128^2 kernel: 256 full-chip blocks (the r15 merge demoted this to a
  // 64-block 25%-utilization tail — measured regression; keep the full-chip shape)
  gemm_nt<0><<<dim3(NDC / 128, NROWS / 128), 256, 0, stream>>>(xb, Wdkvb, ckv, NROWS, NDC, ND);

  // merged uk + uv (shared A = ckv, K = 512): grid (16, 32) = 512 blocks = 2/CU, no tail
  gemm_nt256m<0><<<dim3(16, 32), 512, 0, stream>>>(
      ckv, Wukb, Wuvb, Kbf, Vbf, NROWS, ND, ND, NDC, 8, 1, rope_cos, rope_sin, 1.0f);

  // attention: 512 blocks of 512 threads (QBLK=256, 32 q/wave) — proven v8 config
  flash_attn<<<dim3(8, 64), 512, 0, stream>>>(Qb, Kbf, Vbf, AO);

  // output projection (fp32 out, coalesced LDS epilogue)
  gemm_nt256m<1><<<dim3(8, 32), 512, 0, stream>>>(
      AO, Wob, nullptr, out, nullptr, NROWS, ND, ND, ND, 8, 0, nullptr, nullptr, 0.f);
}